// Round 4
// baseline (338.684 us; speedup 1.0000x reference)
//
#include <hip/hip_runtime.h>
#include <hip/hip_bf16.h>

typedef short bf16x8 __attribute__((ext_vector_type(8)));
typedef short bf16x4 __attribute__((ext_vector_type(4)));
typedef float f32x4  __attribute__((ext_vector_type(4)));
typedef __hip_bfloat16 bf16;

static __device__ __forceinline__ short f2bf(float x) {
    bf16 t = __float2bfloat16(x);
    return *reinterpret_cast<short*>(&t);
}
static __device__ __forceinline__ int pack2(float lo, float hi) {
    union { short s[2]; int i; } u;
    u.s[0] = f2bf(lo); u.s[1] = f2bf(hi);
    return u.i;
}

// ---------------- weight prep: fp32 -> bf16, transposed to [N][K] ----------------
// ws (bf16 elems): qkvT [192][64] @0 ; projT [64][64] @12288 ;
//                  fcT  [256][64] @16384 ; proj2T [64][256] @32768   (96 KB)
__global__ void prep_weights(const float* __restrict__ qkv_w,
                             const float* __restrict__ proj_w,
                             const float* __restrict__ fc_w,
                             const float* __restrict__ proj2_w,
                             bf16* __restrict__ ws) {
    int i = blockIdx.x * blockDim.x + threadIdx.x;
    float v;
    if (i < 12288)      { int n = i >> 6,              k = i & 63;    v = qkv_w[k * 192 + n]; }
    else if (i < 16384) { int j = i - 12288, n = j >> 6, k = j & 63;  v = proj_w[k * 64 + n]; }
    else if (i < 32768) { int j = i - 16384, n = j >> 6, k = j & 63;  v = fc_w[k * 256 + n]; }
    else if (i < 49152) { int j = i - 32768, n = j >> 8, k = j & 255; v = proj2_w[k * 64 + n]; }
    else return;
    ws[i] = __float2bfloat16(v);
}

// ---------------- fused transformer block: wave-private dataflow ----------------
// Each wave owns 16 tokens (tok = w*16 + lr); B-operands are always lane-local.
// LDS (27648 B -> 5 blocks/CU @ VGPR<=102):
//   hbA [4][16][72] @0     per-wave: LN out -> P (unnorm) -> y   (all aliased, wave-private)
//   K   [64][72]    @9216  cross-wave; -> hm [4][16][72] alias in MLP (wave-private)
//   vT  [64][72]    @18432 cross-wave, [h*16+d][tok]
// Barriers: 2 (after QKV K/vT writes; after attention K/vT reads).
__global__ __launch_bounds__(256, 5)
void gpt_block(const float* __restrict__ x,
               const float* __restrict__ ln1_g, const float* __restrict__ ln1_b,
               const float* __restrict__ qkv_b, const float* __restrict__ proj_b,
               const float* __restrict__ ln2_g, const float* __restrict__ ln2_b,
               const float* __restrict__ fc_b,  const float* __restrict__ proj2_b,
               const bf16* __restrict__ ws,
               float* __restrict__ out) {
    __shared__ __align__(16) char smem[27648];
    bf16* Kb = (bf16*)(smem + 9216);    // [64][72]
    bf16* vT = (bf16*)(smem + 18432);   // [64][72]

    const int tid = threadIdx.x;
    const int w   = tid >> 6;          // wave 0..3
    const int l   = tid & 63;
    const int lr  = l & 15;
    const int lk  = l >> 4;
    const int row = w * 16 + lr;       // global token this lane owns
    const size_t b = blockIdx.x;

    bf16* hbw = (bf16*)smem + w * (16 * 72);   // wave-private [16][72]
    bf16* pbw = hbw;                           // alias: P then y
    bf16* hmw = Kb + w * (16 * 72);            // wave-private MLP chunk (over K)

    // ---- phase 0: x tile -> registers (tok=row, f = nt*16+lk*4+r) ----
    f32x4 xr[4];
    {
        const float* xb = x + b * 4096;
        #pragma unroll
        for (int nt = 0; nt < 4; ++nt)
            xr[nt] = *(const f32x4*)&xb[row * 64 + nt * 16 + lk * 4];
    }

    // ---- layernorm: register residual -> hbw (wave-private) ----
    auto ln = [&](const float* g, const float* be) {
        float s0 = 0.f, s1 = 0.f;
        #pragma unroll
        for (int nt = 0; nt < 4; ++nt)
            #pragma unroll
            for (int r = 0; r < 4; ++r) { float v = xr[nt][r]; s0 += v; s1 += v * v; }
        s0 += __shfl_xor(s0, 16); s1 += __shfl_xor(s1, 16);
        s0 += __shfl_xor(s0, 32); s1 += __shfl_xor(s1, 32);
        float mu   = s0 * (1.f / 64.f);
        float var  = s1 * (1.f / 64.f) - mu * mu;
        float rstd = rsqrtf(var + 1e-5f);
        #pragma unroll
        for (int nt = 0; nt < 4; ++nt) {
            f32x4 g4 = ((const f32x4*)g)[nt * 4 + lk];
            f32x4 b4 = ((const f32x4*)be)[nt * 4 + lk];
            bf16x4 o;
            #pragma unroll
            for (int r = 0; r < 4; ++r)
                o[r] = f2bf((xr[nt][r] - mu) * rstd * g4[r] + b4[r]);
            *(bf16x4*)&hbw[lr * 72 + nt * 16 + lk * 4] = o;
        }
    };

    ln(ln1_g, ln1_b);

    // ---- phase 2: QKV — own 16 tokens, all 192 features ----
    int qp[8];                                   // Q regs: qp[2h+j] = f{16h+4lk+2j,+1}, tok=lr
    {
        const short* wsb = (const short*)ws;
        bf16x8 hbf[2];
        #pragma unroll
        for (int ks = 0; ks < 2; ++ks)
            hbf[ks] = *(const bf16x8*)((const short*)hbw + lr * 72 + ks * 32 + lk * 8);

        #pragma unroll
        for (int mt = 0; mt < 4; ++mt) {                    // Q -> registers
            f32x4 acc = {};
            #pragma unroll
            for (int ks = 0; ks < 2; ++ks) {
                bf16x8 a = *(const bf16x8*)(wsb + (mt * 16 + lr) * 64 + ks * 32 + lk * 8);
                acc = __builtin_amdgcn_mfma_f32_16x16x32_bf16(a, hbf[ks], acc, 0, 0, 0);
            }
            f32x4 qb = ((const f32x4*)qkv_b)[mt * 4 + lk];
            qp[2 * mt]     = pack2(acc[0] + qb[0], acc[1] + qb[1]);
            qp[2 * mt + 1] = pack2(acc[2] + qb[2], acc[3] + qb[3]);
        }
        #pragma unroll
        for (int mt = 0; mt < 4; ++mt) {                    // K -> LDS [tok][f]
            f32x4 acc = {};
            #pragma unroll
            for (int ks = 0; ks < 2; ++ks) {
                bf16x8 a = *(const bf16x8*)(wsb + ((64 + mt * 16) + lr) * 64 + ks * 32 + lk * 8);
                acc = __builtin_amdgcn_mfma_f32_16x16x32_bf16(a, hbf[ks], acc, 0, 0, 0);
            }
            f32x4 kb = ((const f32x4*)qkv_b)[16 + mt * 4 + lk];
            bf16x4 o;
            #pragma unroll
            for (int r = 0; r < 4; ++r) o[r] = f2bf(acc[r] + kb[r]);
            *(bf16x4*)&Kb[row * 72 + mt * 16 + lk * 4] = o;
        }
        float vbias0 = qkv_b[128 + lr];                     // V -> vT[f][tok]
        #pragma unroll
        for (int nt = 0; nt < 4; ++nt) {
            f32x4 acc = {};
            #pragma unroll
            for (int ks = 0; ks < 2; ++ks) {
                bf16x8 bfr = *(const bf16x8*)(wsb + ((128 + nt * 16) + lr) * 64 + ks * 32 + lk * 8);
                acc = __builtin_amdgcn_mfma_f32_16x16x32_bf16(hbf[ks], bfr, acc, 0, 0, 0);
            }
            float vb = (nt == 0) ? vbias0 : qkv_b[128 + nt * 16 + lr];
            bf16x4 o;
            #pragma unroll
            for (int r = 0; r < 4; ++r) o[r] = f2bf(acc[r] + vb);
            *(bf16x4*)&vT[(nt * 16 + lr) * 72 + w * 16 + lk * 4] = o;
        }
    }
    __syncthreads();                                        // B1: K, vT visible

    // ---- phase 3: attention (P unnormalized in pbw; normalize y post-PV) ----
    int yp[8];                                              // y regs, same layout as qp
    {
        bf16x4 z = {};
        for (int kt = w + 1; kt < 4; ++kt)                  // zero P tail once
            *(bf16x4*)&pbw[lr * 72 + kt * 16 + lk * 4] = z;

        #pragma unroll
        for (int h = 0; h < 4; ++h) {
            // Q B-frag via butterfly: k=d=8lk+i (lk<2), col=q=lr
            int c0 = qp[2 * h], c1 = qp[2 * h + 1];
            int u0 = __shfl_xor(c0, 16), u1 = __shfl_xor(c1, 16);
            int v0 = __shfl_xor(c0, 32), v1 = __shfl_xor(c1, 32);
            int w0 = __shfl_xor(v0, 16), w1 = __shfl_xor(v1, 16);
            bool odd = (lk & 1);
            union { int i[4]; bf16x8 v; } qu;
            qu.i[0] = odd ? w0 : c0; qu.i[1] = odd ? w1 : c1;
            qu.i[2] = odd ? v0 : u0; qu.i[3] = odd ? v1 : u1;
            bf16x8 qf = qu.v;

            float psum = 0.f;
            for (int kt = 0; kt <= w; ++kt) {               // wave-uniform trip count
                bf16x8 kf = {};
                if (lk < 2)
                    kf = *(const bf16x8*)((const short*)Kb + (kt * 16 + lr) * 72 + h * 16 + lk * 8);
                f32x4 acc = {};
                f32x4 sv = __builtin_amdgcn_mfma_f32_16x16x32_bf16(kf, qf, acc, 0, 0, 0);
                f32x4 e;
                #pragma unroll
                for (int r = 0; r < 4; ++r) {
                    float s = sv[r] * 0.25f;
                    if (kt == w && (4 * lk + r) > lr) s = -1e30f;   // causal mask, diag tile
                    e[r] = __expf(s);
                    psum += e[r];
                }
                *(bf16x4*)&pbw[lr * 72 + kt * 16 + lk * 4] =
                    bf16x4{f2bf(e[0]), f2bf(e[1]), f2bf(e[2]), f2bf(e[3])};
            }
            psum += __shfl_xor(psum, 16);
            psum += __shfl_xor(psum, 32);
            float rinv = __builtin_amdgcn_rcpf(psum);

            // PV: A=vT (d rows), B=P (col=q=lr) -> D[d][q]
            f32x4 y = {};
            #pragma unroll
            for (int ks = 0; ks < 2; ++ks) {
                bf16x8 vf = *(const bf16x8*)((const short*)vT + (h * 16 + lr) * 72 + ks * 32 + lk * 8);
                bf16x8 pf = *(const bf16x8*)((const short*)pbw + lr * 72 + ks * 32 + lk * 8);
                y = __builtin_amdgcn_mfma_f32_16x16x32_bf16(vf, pf, y, 0, 0, 0);
            }
            yp[2 * h]     = pack2(y[0] * rinv, y[1] * rinv);
            yp[2 * h + 1] = pack2(y[2] * rinv, y[3] * rinv);
        }
    }
    __syncthreads();                                        // B2: K/vT reads done (hm overlay)

    // ---- phase 4: y -> pbw (P dead), then attn proj + residual ----
    {
        #pragma unroll
        for (int h = 0; h < 4; ++h) {
            int2 yv = {yp[2 * h], yp[2 * h + 1]};
            *(int2*)&pbw[lr * 72 + h * 16 + lk * 4] = yv;
        }
        const short* wp = (const short*)ws + 12288;
        bf16x8 yf[2];
        #pragma unroll
        for (int ks = 0; ks < 2; ++ks)
            yf[ks] = *(const bf16x8*)((const short*)pbw + lr * 72 + ks * 32 + lk * 8);
        #pragma unroll
        for (int mt = 0; mt < 4; ++mt) {
            f32x4 acc = {};
            #pragma unroll
            for (int ks = 0; ks < 2; ++ks) {
                bf16x8 a = *(const bf16x8*)(wp + (mt * 16 + lr) * 64 + ks * 32 + lk * 8);
                acc = __builtin_amdgcn_mfma_f32_16x16x32_bf16(a, yf[ks], acc, 0, 0, 0);
            }
            f32x4 pb4 = ((const f32x4*)proj_b)[mt * 4 + lk];
            #pragma unroll
            for (int r = 0; r < 4; ++r) xr[mt][r] += acc[r] + pb4[r];
        }
    }

    // ---- phase 5: LN2 (overwrites pbw/hbw; wave-private) ----
    ln(ln2_g, ln2_b);

    // ---- phases 6/7: MLP fused in 64-wide chunks, hidden via wave-private hmw ----
    f32x4 acc2[4] = {f32x4{}, f32x4{}, f32x4{}, f32x4{}};
    {
        const short* wf = (const short*)ws + 16384;
        const short* w2 = (const short*)ws + 32768;
        bf16x8 hbf2[2];
        #pragma unroll
        for (int ks = 0; ks < 2; ++ks)
            hbf2[ks] = *(const bf16x8*)((const short*)hbw + lr * 72 + ks * 32 + lk * 8);

        #pragma unroll
        for (int c = 0; c < 4; ++c) {
            #pragma unroll
            for (int mi = 0; mi < 4; ++mi) {                // fc chunk: f_hid = c*64+mi*16+...
                f32x4 acc = {};
                #pragma unroll
                for (int ks = 0; ks < 2; ++ks) {
                    bf16x8 a = *(const bf16x8*)(wf + ((c * 64 + mi * 16) + lr) * 64 + ks * 32 + lk * 8);
                    acc = __builtin_amdgcn_mfma_f32_16x16x32_bf16(a, hbf2[ks], acc, 0, 0, 0);
                }
                f32x4 fb = ((const f32x4*)fc_b)[(c * 4 + mi) * 4 + lk];
                bf16x4 o;
                #pragma unroll
                for (int r = 0; r < 4; ++r) {
                    float v  = acc[r] + fb[r];
                    float u_ = v * (0.7978845608f + 0.0356774081f * v * v);
                    u_ = fminf(u_, 8.f);
                    float e  = __expf(2.f * u_);
                    o[r] = f2bf(v * e * __builtin_amdgcn_rcpf(1.f + e));
                }
                *(bf16x4*)&hmw[lr * 72 + mi * 16 + lk * 4] = o;
            }
            #pragma unroll
            for (int ks2 = 0; ks2 < 2; ++ks2) {             // proj2 partial (k = c*64+ks2*32+..)
                bf16x8 hf = *(const bf16x8*)((const short*)hmw + lr * 72 + ks2 * 32 + lk * 8);
                #pragma unroll
                for (int mt2 = 0; mt2 < 4; ++mt2) {
                    bf16x8 a = *(const bf16x8*)(w2 + (mt2 * 16 + lr) * 256 + c * 64 + ks2 * 32 + lk * 8);
                    acc2[mt2] = __builtin_amdgcn_mfma_f32_16x16x32_bf16(a, hf, acc2[mt2], 0, 0, 0);
                }
            }
        }
    }

    // ---- epilogue: out = residual + proj2 + bias (orientations match exactly) ----
    {
        float* ob = out + b * 4096;
        #pragma unroll
        for (int nt = 0; nt < 4; ++nt) {
            f32x4 b2 = ((const f32x4*)proj2_b)[nt * 4 + lk];
            f32x4 o;
            #pragma unroll
            for (int r = 0; r < 4; ++r) o[r] = xr[nt][r] + acc2[nt][r] + b2[r];
            *(f32x4*)&ob[row * 64 + nt * 16 + lk * 4] = o;
        }
    }
}

extern "C" void kernel_launch(void* const* d_in, const int* in_sizes, int n_in,
                              void* d_out, int out_size, void* d_ws, size_t ws_size,
                              hipStream_t stream) {
    const float* x       = (const float*)d_in[0];
    const float* ln1_g   = (const float*)d_in[1];
    const float* ln1_b   = (const float*)d_in[2];
    const float* qkv_w   = (const float*)d_in[3];
    const float* qkv_b   = (const float*)d_in[4];
    const float* proj_w  = (const float*)d_in[5];
    const float* proj_b  = (const float*)d_in[6];
    const float* ln2_g   = (const float*)d_in[7];
    const float* ln2_b   = (const float*)d_in[8];
    const float* fc_w    = (const float*)d_in[9];
    const float* fc_b    = (const float*)d_in[10];
    const float* proj2_w = (const float*)d_in[11];
    const float* proj2_b = (const float*)d_in[12];
    bf16* ws   = (bf16*)d_ws;
    float* out = (float*)d_out;

    prep_weights<<<192, 256, 0, stream>>>(qkv_w, proj_w, fc_w, proj2_w, ws);
    gpt_block<<<4096, 256, 0, stream>>>(x, ln1_g, ln1_b, qkv_b, proj_b,
                                        ln2_g, ln2_b, fc_b, proj2_b, ws, out);
}